// Round 1
// baseline (818.662 us; speedup 1.0000x reference)
//
#include <hip/hip_runtime.h>

// MatrixMemory: y = state @ query (batched mat-vec), dM = d_out ⊗ key (outer).
// B=2048, DV=DK=256. Pure HBM-streaming problem: ~1.08 GB traffic, ~172 us floor
// at 6.3 TB/s achievable. One wave per (b,v) row: 64 lanes x float4 = 256 floats.

#define B_SZ 2048
#define DK_SZ 256
#define DV_SZ 256

typedef float f32x4 __attribute__((ext_vector_type(4)));

__global__ __launch_bounds__(256) void MatrixMemory_kernel(
    const float* __restrict__ state,   // (B, DV, DK)
    const float* __restrict__ query,   // (B, DK)
    const float* __restrict__ key,     // (B, DK)
    const float* __restrict__ dout,    // (B, DV)
    float* __restrict__ y,             // (B, DV)
    float* __restrict__ dM)            // (B, DV, DK)
{
    const int tid  = threadIdx.x;
    const int lane = tid & 63;
    const int wid  = tid >> 6;

    // global wave id == flattened (b, v) row index in [0, B*DV)
    const size_t w = (size_t)blockIdx.x * 4 + wid;
    const int b = (int)(w >> 8);               // DV = 256

    const size_t srow = w * (size_t)DK_SZ + (size_t)(lane << 2);   // state/dM row offset
    const size_t qoff = (size_t)b * DK_SZ + (size_t)(lane << 2);   // query/key offset

    // streaming 537 MB read: nontemporal (no reuse, keep L2 for q/k/dout)
    const f32x4 s4 = __builtin_nontemporal_load(
        reinterpret_cast<const f32x4*>(state + srow));
    // q/k/dout have 64x reuse within a batch -> normal (cached) loads
    const f32x4 q4 = *reinterpret_cast<const f32x4*>(query + qoff);
    const f32x4 k4 = *reinterpret_cast<const f32x4*>(key + qoff);
    const float dob = dout[w];                 // wave-uniform broadcast

    // ---- y[b,v] = dot(state row, query row) ----
    float p = s4.x * q4.x + s4.y * q4.y + s4.z * q4.z + s4.w * q4.w;
    #pragma unroll
    for (int off = 32; off > 0; off >>= 1)
        p += __shfl_xor(p, off, 64);
    if (lane == 0) y[w] = p;

    // ---- dM row = d_out[b,v] * key row ---- (537 MB streaming write)
    f32x4 dm;
    dm.x = dob * k4.x;
    dm.y = dob * k4.y;
    dm.z = dob * k4.z;
    dm.w = dob * k4.w;
    __builtin_nontemporal_store(dm, reinterpret_cast<f32x4*>(dM + srow));
}

extern "C" void kernel_launch(void* const* d_in, const int* in_sizes, int n_in,
                              void* d_out, int out_size, void* d_ws, size_t ws_size,
                              hipStream_t stream) {
    const float* state = (const float*)d_in[0];
    const float* query = (const float*)d_in[1];
    const float* key   = (const float*)d_in[2];
    const float* dout  = (const float*)d_in[3];

    float* y  = (float*)d_out;                       // first B*DV floats
    float* dM = y + (size_t)B_SZ * DV_SZ;            // then B*DV*DK floats

    const int rows = B_SZ * DV_SZ;                   // 524288 waves, 4 per block
    MatrixMemory_kernel<<<dim3(rows / 4), dim3(256), 0, stream>>>(
        state, query, key, dout, y, dM);
}